// Round 1
// baseline (236.793 us; speedup 1.0000x reference)
//
#include <hip/hip_runtime.h>

typedef unsigned short u16;
typedef __attribute__((ext_vector_type(8))) short short8;
typedef __attribute__((ext_vector_type(4))) float f32x4;
typedef __attribute__((ext_vector_type(4))) unsigned short u16x4;

#define DEVINL __device__ __forceinline__

DEVINL u16 f2bf(float f) {
    union { float f; unsigned u; } x; x.f = f;
    unsigned u = x.u;
    u += 0x7fffu + ((u >> 16) & 1u);   // round-to-nearest-even
    return (u16)(u >> 16);
}

DEVINL void gload_lds16(const void* g, void* l) {
    __builtin_amdgcn_global_load_lds(
        (const __attribute__((address_space(1))) unsigned*)g,
        (__attribute__((address_space(3))) unsigned*)l, 16, 0, 0);
}

// ---------------- convert x (fp32 -> bf16), vectorized ----------------
__global__ void k_conv_x(const float* __restrict__ in, u16* __restrict__ out, int n4) {
    int i = blockIdx.x * blockDim.x + threadIdx.x;
    int stride = gridDim.x * blockDim.x;
    for (; i < n4; i += stride) {
        float4 v = ((const float4*)in)[i];
        u16x4 o;
        o.x = f2bf(v.x); o.y = f2bf(v.y); o.z = f2bf(v.z); o.w = f2bf(v.w);
        ((u16x4*)out)[i] = o;
    }
}

// ---------------- transpose + convert: in [R][C] fp32 -> out [C][R] bf16 ----------------
__global__ void k_transpose_bf(const float* __restrict__ in, u16* __restrict__ out, int R, int C) {
    __shared__ float t[32][33];
    int c0 = blockIdx.x * 32, r0 = blockIdx.y * 32;
    int tx = threadIdx.x, ty = threadIdx.y;
    #pragma unroll
    for (int j = 0; j < 32; j += 8)
        t[ty + j][tx] = in[(size_t)(r0 + ty + j) * C + c0 + tx];
    __syncthreads();
    #pragma unroll
    for (int j = 0; j < 32; j += 8)
        out[(size_t)(c0 + ty + j) * R + r0 + tx] = f2bf(t[tx][ty + j]);
}

// ---------------- GEMM C[M][N] = A[M][K] @ BT[N][K]^T  (bf16 in, bf16/f32 out) ----------------
// 128x128 tile, BK=32, 4 waves (each 64x64), m97 structure.
template<bool OUT_BF16>
__global__ __launch_bounds__(256, 2)
void k_gemm_bt(const u16* __restrict__ A, const u16* __restrict__ BT,
               void* __restrict__ C, int N, int K) {
    __shared__ u16 Asm[128 * 32];
    __shared__ u16 Bsm[128 * 32];
    const int tid  = threadIdx.x;
    const int lane = tid & 63;
    const int wave = tid >> 6;
    const long row0 = (long)blockIdx.y * 128;
    const long col0 = (long)blockIdx.x * 128;
    const int  wr = (wave >> 1) * 64;
    const int  wc = (wave & 1) * 64;

    f32x4 acc[4][4] = {};

    const int ar0 = lane >> 2;        // row-in-chunk 0..15
    const int ak  = (lane & 3) * 8;   // k offset 0,8,16,24

    for (int kb = 0; kb < K; kb += 32) {
        #pragma unroll
        for (int i = 0; i < 2; i++) {
            int ch = wave * 2 + i;           // 0..7
            int r  = ch * 16 + ar0;          // 0..127
            gload_lds16(A  + (row0 + r) * (size_t)K + kb + ak, &Asm[ch * 512]);
            gload_lds16(BT + (col0 + r) * (size_t)K + kb + ak, &Bsm[ch * 512]);
        }
        __syncthreads();
        short8 af[4], bfr[4];
        #pragma unroll
        for (int m = 0; m < 4; m++)
            af[m] = *(const short8*)&Asm[(wr + m * 16 + (lane & 15)) * 32 + (lane >> 4) * 8];
        #pragma unroll
        for (int n = 0; n < 4; n++)
            bfr[n] = *(const short8*)&Bsm[(wc + n * 16 + (lane & 15)) * 32 + (lane >> 4) * 8];
        #pragma unroll
        for (int m = 0; m < 4; m++)
            #pragma unroll
            for (int n = 0; n < 4; n++)
                acc[m][n] = __builtin_amdgcn_mfma_f32_16x16x32_bf16(af[m], bfr[n], acc[m][n], 0, 0, 0);
        __syncthreads();
    }

    const int rl = (lane >> 4) * 4;
    const int cl = lane & 15;
    #pragma unroll
    for (int m = 0; m < 4; m++)
        #pragma unroll
        for (int n = 0; n < 4; n++)
            #pragma unroll
            for (int r = 0; r < 4; r++) {
                long row = row0 + wr + m * 16 + rl + r;
                long col = col0 + wc + n * 16 + cl;
                if constexpr (OUT_BF16)
                    ((u16*)C)[row * (size_t)N + col] = f2bf(acc[m][n][r]);
                else
                    ((float*)C)[row * (size_t)N + col] = acc[m][n][r];
            }
}

// ---------------- Flash attention (causal), bf16 in/out ----------------
// grid: (S/64, B*H). Block = 4 waves; wave w owns q rows q0+16w .. q0+16w+15.
#define SCALE_L2E 0.18033688011112042f  // (1/sqrt(64)) * log2(e)

__global__ __launch_bounds__(256, 2)
void k_attn(const u16* __restrict__ qkv, u16* __restrict__ y) {
    constexpr int S = 1024, E = 1024, TE = 3072;
    __shared__ u16 Kt[64 * 72];       // [kv][d], padded rows (144B)
    __shared__ u16 Vt[64 * 72];       // [d][kv], padded rows
    __shared__ u16 Pl[4][16 * 72];    // per-wave P tile [q][kv], padded

    const int tid  = threadIdx.x;
    const int lane = tid & 63;
    const int wave = tid >> 6;
    const int b  = blockIdx.y >> 4;
    const int h  = blockIdx.y & 15;
    const int q0 = blockIdx.x * 64;
    const size_t rowbase = (size_t)b * S;

    const int qrow = q0 + wave * 16 + (lane & 15);

    short8 aq[2];
    {
        const u16* qp = qkv + (rowbase + qrow) * TE + h * 64 + (lane >> 4) * 8;
        aq[0] = *(const short8*)qp;
        aq[1] = *(const short8*)(qp + 32);
    }

    f32x4 o[4] = {};
    float mrow[4] = {-1e30f, -1e30f, -1e30f, -1e30f};
    float lrow[4] = {0.f, 0.f, 0.f, 0.f};

    const int ntiles = blockIdx.x + 1;
    for (int t = 0; t < ntiles; ++t) {
        const int kv0 = t * 64;
        // stage K tile [64][64] row-major (padded to 72)
        #pragma unroll
        for (int i = 0; i < 2; i++) {
            int ch = tid * 2 + i;
            int r  = ch >> 3;
            int c  = (ch & 7) * 8;
            short8 kd = *(const short8*)(qkv + (rowbase + kv0 + r) * TE + E + h * 64 + c);
            *(short8*)&Kt[r * 72 + c] = kd;
        }
        // stage V^T: Vt[d][kv]; each wave covers 16 kv rows, lane = d
        {
            int d  = lane;
            int r0 = wave * 16;
            const u16* vp = qkv + (rowbase + kv0 + r0) * TE + 2 * E + h * 64 + d;
            u16 vv[16];
            #pragma unroll
            for (int j = 0; j < 16; j++) vv[j] = vp[(size_t)j * TE];
            short8 w0, w1;
            #pragma unroll
            for (int j = 0; j < 8; j++) { w0[j] = (short)vv[j]; w1[j] = (short)vv[j + 8]; }
            *(short8*)&Vt[d * 72 + r0]     = w0;
            *(short8*)&Vt[d * 72 + r0 + 8] = w1;
        }
        __syncthreads();

        // QK^T : 16 q-rows x 64 kv
        f32x4 s[4];
        #pragma unroll
        for (int f = 0; f < 4; f++) {
            f32x4 z = {};
            #pragma unroll
            for (int kk = 0; kk < 2; kk++) {
                short8 bk = *(const short8*)&Kt[(f * 16 + (lane & 15)) * 72 + kk * 32 + (lane >> 4) * 8];
                z = __builtin_amdgcn_mfma_f32_16x16x32_bf16(aq[kk], bk, z, 0, 0, 0);
            }
            s[f] = z;
        }

        if (t == ntiles - 1) {   // diagonal tile: causal mask
            #pragma unroll
            for (int f = 0; f < 4; f++) {
                int col = kv0 + f * 16 + (lane & 15);
                #pragma unroll
                for (int r = 0; r < 4; r++) {
                    int row = q0 + wave * 16 + (lane >> 4) * 4 + r;
                    if (col > row) s[f][r] = -1e30f;
                }
            }
        }

        // online softmax (scale folded into exp2)
        float p[4][4];
        #pragma unroll
        for (int r = 0; r < 4; r++) {
            float v = fmaxf(fmaxf(s[0][r], s[1][r]), fmaxf(s[2][r], s[3][r]));
            v = fmaxf(v, __shfl_xor(v, 1));
            v = fmaxf(v, __shfl_xor(v, 2));
            v = fmaxf(v, __shfl_xor(v, 4));
            v = fmaxf(v, __shfl_xor(v, 8));
            float mnew  = fmaxf(mrow[r], v);
            float alpha = exp2f((mrow[r] - mnew) * SCALE_L2E);
            mrow[r] = mnew;
            float rs = 0.f;
            #pragma unroll
            for (int f = 0; f < 4; f++) {
                float pv = exp2f((s[f][r] - mnew) * SCALE_L2E);
                p[f][r] = pv;
                rs += pv;
            }
            rs += __shfl_xor(rs, 1);
            rs += __shfl_xor(rs, 2);
            rs += __shfl_xor(rs, 4);
            rs += __shfl_xor(rs, 8);
            lrow[r] = lrow[r] * alpha + rs;
            #pragma unroll
            for (int df = 0; df < 4; df++) o[df][r] *= alpha;
        }

        // P (C-layout) -> LDS -> A-layout
        #pragma unroll
        for (int f = 0; f < 4; f++)
            #pragma unroll
            for (int r = 0; r < 4; r++)
                Pl[wave][((lane >> 4) * 4 + r) * 72 + f * 16 + (lane & 15)] = f2bf(p[f][r]);

        // PV
        #pragma unroll
        for (int kk = 0; kk < 2; kk++) {
            short8 ap = *(const short8*)&Pl[wave][(lane & 15) * 72 + kk * 32 + (lane >> 4) * 8];
            #pragma unroll
            for (int df = 0; df < 4; df++) {
                short8 bv = *(const short8*)&Vt[(df * 16 + (lane & 15)) * 72 + kk * 32 + (lane >> 4) * 8];
                o[df] = __builtin_amdgcn_mfma_f32_16x16x32_bf16(ap, bv, o[df], 0, 0, 0);
            }
        }
        __syncthreads();
    }

    // epilogue: y[b][q][h*64+d] bf16
    #pragma unroll
    for (int df = 0; df < 4; df++)
        #pragma unroll
        for (int r = 0; r < 4; r++) {
            int row = q0 + wave * 16 + (lane >> 4) * 4 + r;
            y[(rowbase + row) * E + h * 64 + df * 16 + (lane & 15)] = f2bf(o[df][r] / lrow[r]);
        }
}

// ---------------- launch ----------------
extern "C" void kernel_launch(void* const* d_in, const int* in_sizes, int n_in,
                              void* d_out, int out_size, void* d_ws, size_t ws_size,
                              hipStream_t stream) {
    const float* x     = (const float*)d_in[0];   // [8,1024,1024]
    const float* Wattn = (const float*)d_in[1];   // [1024,3072]
    const float* Wproj = (const float*)d_in[2];   // [1024,1024]
    float* out = (float*)d_out;                   // [8,1024,1024] fp32

    char* ws = (char*)d_ws;
    u16* buf0 = (u16*)ws;                                  // x_bf16, later y_bf16 (16.78 MB)
    u16* wT   = (u16*)(ws + 16777216);                     // W^T bf16 (6.29 MB, reused)
    u16* qkv  = (u16*)(ws + 16777216 + 6291456);           // [8192][3072] bf16 (50.3 MB)

    // x -> bf16
    k_conv_x<<<2048, 256, 0, stream>>>(x, buf0, 8388608 / 4);
    // W_attn^T -> bf16 [3072][1024]
    k_transpose_bf<<<dim3(3072 / 32, 1024 / 32), dim3(32, 8), 0, stream>>>(Wattn, wT, 1024, 3072);
    // qkv = x @ W_attn   (bf16 out)
    k_gemm_bt<true><<<dim3(3072 / 128, 8192 / 128), 256, 0, stream>>>(buf0, wT, qkv, 3072, 1024);
    // W_proj^T -> bf16 [1024][1024] (overwrites wT; GEMM1 already done in stream order)
    k_transpose_bf<<<dim3(1024 / 32, 1024 / 32), dim3(32, 8), 0, stream>>>(Wproj, wT, 1024, 1024);
    // flash attention -> y (reuses buf0)
    k_attn<<<dim3(1024 / 64, 8 * 16), 256, 0, stream>>>(qkv, buf0);
    // out = y @ W_proj  (fp32 out)
    k_gemm_bt<false><<<dim3(1024 / 128, 8192 / 128), 256, 0, stream>>>(buf0, wT, out, 1024, 1024);
}

// Round 2
// 170.692 us; speedup vs baseline: 1.3873x; 1.3873x over previous
//
#include <hip/hip_runtime.h>
#include <hip/hip_bf16.h>

typedef unsigned short u16;
typedef __attribute__((ext_vector_type(8))) short short8;
typedef __attribute__((ext_vector_type(4))) float f32x4;
typedef __attribute__((ext_vector_type(4))) unsigned short u16x4;

#define DEVINL __device__ __forceinline__

DEVINL u16 f2bf(float f) {
    union { float f; unsigned u; } x; x.f = f;
    unsigned u = x.u;
    u += 0x7fffu + ((u >> 16) & 1u);   // round-to-nearest-even
    return (u16)(u >> 16);
}

DEVINL void gload_lds16(const void* g, void* l) {
    __builtin_amdgcn_global_load_lds(
        (const __attribute__((address_space(1))) unsigned*)g,
        (__attribute__((address_space(3))) unsigned*)l, 16, 0, 0);
}

// XOR swizzle for 128B-stride LDS rows: spreads 16B slots across banks.
DEVINL int swz(int row) { return (((row & 7) ^ ((row >> 3) & 7)) << 4); }

// ---------------- convert x (fp32 -> bf16), vectorized ----------------
__global__ void k_conv_x(const float* __restrict__ in, u16* __restrict__ out, int n4) {
    int i = blockIdx.x * blockDim.x + threadIdx.x;
    int stride = gridDim.x * blockDim.x;
    for (; i < n4; i += stride) {
        float4 v = ((const float4*)in)[i];
        u16x4 o;
        o.x = f2bf(v.x); o.y = f2bf(v.y); o.z = f2bf(v.z); o.w = f2bf(v.w);
        ((u16x4*)out)[i] = o;
    }
}

// ---------------- transpose + convert: in [R][C] fp32 -> out [C][R] bf16 ----------------
__global__ void k_transpose_bf(const float* __restrict__ in, u16* __restrict__ out, int R, int C) {
    __shared__ float t[32][33];
    int c0 = blockIdx.x * 32, r0 = blockIdx.y * 32;
    int tx = threadIdx.x, ty = threadIdx.y;
    #pragma unroll
    for (int j = 0; j < 32; j += 8)
        t[ty + j][tx] = in[(size_t)(r0 + ty + j) * C + c0 + tx];
    __syncthreads();
    #pragma unroll
    for (int j = 0; j < 32; j += 8)
        out[(size_t)(c0 + ty + j) * R + r0 + tx] = f2bf(t[tx][ty + j]);
}

// ---------------- GEMM C[M][N] = A[M][K] @ BT[N][K]^T  (bf16 in, bf16/f32 out) ----------------
// 128x128 tile, BK=32, 4 waves (each 64x64), m97 structure + XCD-bijective swizzle.
template<bool OUT_BF16>
__global__ __launch_bounds__(256, 2)
void k_gemm_bt(const u16* __restrict__ A, const u16* __restrict__ BT,
               void* __restrict__ C, int N, int K) {
    __shared__ u16 Asm[128 * 32];
    __shared__ u16 Bsm[128 * 32];
    const int tid  = threadIdx.x;
    const int lane = tid & 63;
    const int wave = tid >> 6;

    // XCD-aware bijective block swizzle (nwg % 8 == 0 for our grids)
    const int gx   = gridDim.x;
    const int nwg  = gx * gridDim.y;
    const int orig = blockIdx.y * gx + blockIdx.x;
    const int wg   = (orig & 7) * (nwg >> 3) + (orig >> 3);
    const int bx   = wg % gx;
    const int by   = wg / gx;

    const long row0 = (long)by * 128;
    const long col0 = (long)bx * 128;
    const int  wr = (wave >> 1) * 64;
    const int  wc = (wave & 1) * 64;

    f32x4 acc[4][4] = {};

    const int ar0 = lane >> 2;        // row-in-chunk 0..15
    const int ak  = (lane & 3) * 8;   // k offset 0,8,16,24

    for (int kb = 0; kb < K; kb += 32) {
        #pragma unroll
        for (int i = 0; i < 2; i++) {
            int ch = wave * 2 + i;           // 0..7
            int r  = ch * 16 + ar0;          // 0..127
            gload_lds16(A  + (row0 + r) * (size_t)K + kb + ak, &Asm[ch * 512]);
            gload_lds16(BT + (col0 + r) * (size_t)K + kb + ak, &Bsm[ch * 512]);
        }
        __syncthreads();
        short8 af[4], bfr[4];
        #pragma unroll
        for (int m = 0; m < 4; m++)
            af[m] = *(const short8*)&Asm[(wr + m * 16 + (lane & 15)) * 32 + (lane >> 4) * 8];
        #pragma unroll
        for (int n = 0; n < 4; n++)
            bfr[n] = *(const short8*)&Bsm[(wc + n * 16 + (lane & 15)) * 32 + (lane >> 4) * 8];
        #pragma unroll
        for (int m = 0; m < 4; m++)
            #pragma unroll
            for (int n = 0; n < 4; n++)
                acc[m][n] = __builtin_amdgcn_mfma_f32_16x16x32_bf16(af[m], bfr[n], acc[m][n], 0, 0, 0);
        __syncthreads();
    }

    const int rl = (lane >> 4) * 4;
    const int cl = lane & 15;
    #pragma unroll
    for (int m = 0; m < 4; m++)
        #pragma unroll
        for (int n = 0; n < 4; n++)
            #pragma unroll
            for (int r = 0; r < 4; r++) {
                long row = row0 + wr + m * 16 + rl + r;
                long col = col0 + wc + n * 16 + cl;
                if constexpr (OUT_BF16)
                    ((u16*)C)[row * (size_t)N + col] = f2bf(acc[m][n][r]);
                else
                    ((float*)C)[row * (size_t)N + col] = acc[m][n][r];
            }
}

// ---------------- Flash attention (causal), bf16 in/out ----------------
// 1D grid, longest-first: blocks 0..127 are the 16-tile (diagonal-last) columns.
// Block = 4 waves; wave w owns q rows q0+16w .. q0+16w+15.
#define SCALE_L2E 0.18033688011112042f  // (1/sqrt(64)) * log2(e)

__global__ __launch_bounds__(256, 2)
void k_attn(const u16* __restrict__ qkv, u16* __restrict__ y) {
    constexpr int S = 1024, E = 1024, TE = 3072;
    // stride-64 (128B) rows, XOR-swizzled
    __shared__ u16 Kt[64 * 64];        // [kv][d]
    __shared__ u16 Vt[80 * 64];        // [d][kv]; row 64 = ones (sum col), 65..79 = zeros
    __shared__ u16 Pl[4][16 * 64];     // per-wave P [q][kv]

    const int tid  = threadIdx.x;
    const int lane = tid & 63;
    const int lo   = lane & 15;
    const int hi   = lane >> 4;
    const int wave = tid >> 6;

    const int qi = 15 - (int)(blockIdx.x >> 7);   // longest first
    const int bh = blockIdx.x & 127;
    const int b  = bh >> 4;
    const int h  = bh & 15;
    const int q0 = qi * 64;
    const size_t rowbase = (size_t)b * S;

    // init Vt rows 64..79: row 64 = bf16 1.0, rest 0
    for (int i = tid; i < 16 * 64; i += 256)
        Vt[64 * 64 + i] = (i < 64) ? (u16)0x3F80 : (u16)0;

    // Q fragment (held in regs across all tiles)
    const int qrow = q0 + wave * 16 + lo;
    short8 aq[2];
    {
        const u16* qp = qkv + (rowbase + qrow) * TE + h * 64 + hi * 8;
        aq[0] = *(const short8*)qp;
        aq[1] = *(const short8*)(qp + 32);
    }

    f32x4 o[4] = {};
    f32x4 o5 = {};                      // sum column (l) via ones-row MFMA
    float mrow[4] = {-1e30f, -1e30f, -1e30f, -1e30f};

    // staging indices
    const int kr0 = (wave << 3) + (lane >> 3);   // K dest row (it=0)
    const int kcb = (lane & 7) * 16;             // K dest in-row byte
    const int vkv = (tid >> 3) * 2;              // V: even kv row
    const int vdc = (tid & 7) * 8;               // V: d chunk base

    const int ntiles = qi + 1;
    for (int t = 0; t < ntiles; ++t) {
        const int kv0 = t * 64;
        __syncthreads();   // previous tile's reads done before overwrite (also covers Vt init)

        // ---- stage K via global_load_lds with pre-swizzled source ----
        #pragma unroll
        for (int it = 0; it < 2; it++) {
            int r = kr0 + it * 32;
            const char* src = (const char*)qkv
                + (((rowbase + kv0 + r) * TE + E + h * 64) << 1) + (kcb ^ swz(r));
            gload_lds16(src, (char*)Kt + wave * 1024 + it * 4096);
        }
        // ---- stage V^T: coalesced row loads, swizzled b32 pair writes ----
        {
            const u16* vsrc = qkv + (rowbase + kv0 + vkv) * TE + 2 * E + h * 64 + vdc;
            short8 v0 = *(const short8*)vsrc;
            short8 v1 = *(const short8*)(vsrc + TE);
            #pragma unroll
            for (int j = 0; j < 8; j++) {
                int d = vdc + j;
                unsigned val = (unsigned)(u16)v0[j] | ((unsigned)(u16)v1[j] << 16);
                *(unsigned*)((char*)Vt + d * 128 + ((vkv * 2) ^ swz(d))) = val;
            }
        }
        __syncthreads();

        // ---- QK^T : 16 q-rows x 64 kv ----
        f32x4 s[4];
        #pragma unroll
        for (int f = 0; f < 4; f++) {
            f32x4 z = {};
            #pragma unroll
            for (int kk = 0; kk < 2; kk++) {
                int row = f * 16 + lo;
                short8 bk = *(const short8*)((const char*)Kt + row * 128
                              + ((kk * 64 + hi * 16) ^ swz(row)));
                z = __builtin_amdgcn_mfma_f32_16x16x32_bf16(aq[kk], bk, z, 0, 0, 0);
            }
            s[f] = z;
        }

        if (t == ntiles - 1) {   // diagonal tile: causal mask
            #pragma unroll
            for (int f = 0; f < 4; f++) {
                int col = kv0 + f * 16 + lo;
                #pragma unroll
                for (int r = 0; r < 4; r++) {
                    int row = q0 + wave * 16 + hi * 4 + r;
                    if (col > row) s[f][r] = -1e30f;
                }
            }
        }

        // ---- online softmax: max + defer-rescale; sum comes from MFMA ----
        float vmax[4];
        #pragma unroll
        for (int r = 0; r < 4; r++) {
            float v = fmaxf(fmaxf(s[0][r], s[1][r]), fmaxf(s[2][r], s[3][r]));
            v = fmaxf(v, __shfl_xor(v, 1));
            v = fmaxf(v, __shfl_xor(v, 2));
            v = fmaxf(v, __shfl_xor(v, 4));
            v = fmaxf(v, __shfl_xor(v, 8));
            vmax[r] = v;
        }
        bool need = false;
        #pragma unroll
        for (int r = 0; r < 4; r++)
            need |= ((vmax[r] - mrow[r]) * SCALE_L2E > 8.0f);
        if (__any(need)) {
            #pragma unroll
            for (int r = 0; r < 4; r++) {
                float mnew  = fmaxf(mrow[r], vmax[r]);
                float alpha = exp2f((mrow[r] - mnew) * SCALE_L2E);
                mrow[r] = mnew;
                #pragma unroll
                for (int df = 0; df < 4; df++) o[df][r] *= alpha;
                o5[r] *= alpha;
            }
        }

        // ---- P = exp2((s - m) * scale) -> bf16 -> swizzled LDS ----
        #pragma unroll
        for (int f = 0; f < 4; f++)
            #pragma unroll
            for (int r = 0; r < 4; r++) {
                float pv = exp2f((s[f][r] - mrow[r]) * SCALE_L2E);
                int q = hi * 4 + r;
                *(u16*)((char*)&Pl[wave][0] + q * 128 + ((f * 32 + lo * 2) ^ swz(q)))
                    = f2bf(pv);
            }

        // ---- PV (+ sum column): same-wave P readback, no barrier needed ----
        #pragma unroll
        for (int kk = 0; kk < 2; kk++) {
            short8 ap = *(const short8*)((const char*)&Pl[wave][0] + lo * 128
                          + ((kk * 64 + hi * 16) ^ swz(lo)));
            #pragma unroll
            for (int df = 0; df < 4; df++) {
                int row = df * 16 + lo;
                short8 bv = *(const short8*)((const char*)Vt + row * 128
                              + ((kk * 64 + hi * 16) ^ swz(row)));
                o[df] = __builtin_amdgcn_mfma_f32_16x16x32_bf16(ap, bv, o[df], 0, 0, 0);
            }
            {
                int row = 64 + lo;
                short8 bv = *(const short8*)((const char*)Vt + row * 128
                              + ((kk * 64 + hi * 16) ^ swz(row)));
                o5 = __builtin_amdgcn_mfma_f32_16x16x32_bf16(ap, bv, o5, 0, 0, 0);
            }
        }
    }

    // ---- epilogue: l lives in lanes lo==0 of o5; broadcast, divide, store ----
    float rinv[4];
    #pragma unroll
    for (int r = 0; r < 4; r++) {
        float l = __shfl(o5[r], hi << 4);
        rinv[r] = 1.0f / l;
    }
    #pragma unroll
    for (int df = 0; df < 4; df++)
        #pragma unroll
        for (int r = 0; r < 4; r++) {
            int row = q0 + wave * 16 + hi * 4 + r;
            y[(rowbase + row) * E + h * 64 + df * 16 + lo] = f2bf(o[df][r] * rinv[r]);
        }
}

// ---------------- launch ----------------
extern "C" void kernel_launch(void* const* d_in, const int* in_sizes, int n_in,
                              void* d_out, int out_size, void* d_ws, size_t ws_size,
                              hipStream_t stream) {
    const float* x     = (const float*)d_in[0];   // [8,1024,1024]
    const float* Wattn = (const float*)d_in[1];   // [1024,3072]
    const float* Wproj = (const float*)d_in[2];   // [1024,1024]
    float* out = (float*)d_out;                   // [8,1024,1024] fp32

    char* ws = (char*)d_ws;
    u16* buf0 = (u16*)ws;                                  // x_bf16, later y_bf16 (16.78 MB)
    u16* wT   = (u16*)(ws + 16777216);                     // W^T bf16 (6.29 MB, reused)
    u16* qkv  = (u16*)(ws + 16777216 + 6291456);           // [8192][3072] bf16 (50.3 MB)

    // x -> bf16
    k_conv_x<<<2048, 256, 0, stream>>>(x, buf0, 8388608 / 4);
    // W_attn^T -> bf16 [3072][1024]
    k_transpose_bf<<<dim3(3072 / 32, 1024 / 32), dim3(32, 8), 0, stream>>>(Wattn, wT, 1024, 3072);
    // qkv = x @ W_attn   (bf16 out)
    k_gemm_bt<true><<<dim3(3072 / 128, 8192 / 128), 256, 0, stream>>>(buf0, wT, qkv, 3072, 1024);
    // W_proj^T -> bf16 [1024][1024] (overwrites wT; GEMM1 already done in stream order)
    k_transpose_bf<<<dim3(1024 / 32, 1024 / 32), dim3(32, 8), 0, stream>>>(Wproj, wT, 1024, 1024);
    // flash attention -> y (reuses buf0)
    k_attn<<<dim3(2048), 256, 0, stream>>>(qkv, buf0);
    // out = y @ W_proj  (fp32 out)
    k_gemm_bt<false><<<dim3(1024 / 128, 8192 / 128), 256, 0, stream>>>(buf0, wT, out, 1024, 1024);
}

// Round 4
// 149.493 us; speedup vs baseline: 1.5840x; 1.1418x over previous
//
#include <hip/hip_runtime.h>
#include <hip/hip_bf16.h>

typedef unsigned short u16;
typedef __attribute__((ext_vector_type(8))) short short8;
typedef __attribute__((ext_vector_type(4))) float f32x4;
typedef __attribute__((ext_vector_type(16))) float f32x16;
typedef __attribute__((ext_vector_type(4))) unsigned short u16x4;

#define DEVINL __device__ __forceinline__

DEVINL u16 f2bf(float f) {
    union { float f; unsigned u; } x; x.f = f;
    unsigned u = x.u;
    u += 0x7fffu + ((u >> 16) & 1u);   // round-to-nearest-even
    return (u16)(u >> 16);
}

DEVINL void gload_lds16(const void* g, void* l) {
    __builtin_amdgcn_global_load_lds(
        (const __attribute__((address_space(1))) unsigned*)g,
        (__attribute__((address_space(3))) unsigned*)l, 16, 0, 0);
}

// XOR swizzle for 128B-stride LDS rows: spreads 16B slots across banks.
DEVINL int swz(int row) { return (((row & 7) ^ ((row >> 3) & 7)) << 4); }

// v_permlane32_swap: after call, for lane<32: a=own a, b=partner's a;
// for lane>=32: a=partner's b, b=own b.
DEVINL void swap32(unsigned& a, unsigned& b) {
#if __has_builtin(__builtin_amdgcn_permlane32_swap)
    typedef __attribute__((ext_vector_type(2))) unsigned uv2;
    uv2 r = __builtin_amdgcn_permlane32_swap(a, b, false, false);
    a = r.x; b = r.y;
#else
    int h = ((int)(threadIdx.x & 63)) >> 5;
    unsigned pa = (unsigned)__shfl_xor((int)a, 32);
    unsigned pb = (unsigned)__shfl_xor((int)b, 32);
    unsigned na = h ? pb : a;
    unsigned nb = h ? b : pa;
    a = na; b = nb;
#endif
}

// ---------------- convert x (fp32 -> bf16), vectorized ----------------
__global__ void k_conv_x(const float* __restrict__ in, u16* __restrict__ out, int n4) {
    int i = blockIdx.x * blockDim.x + threadIdx.x;
    int stride = gridDim.x * blockDim.x;
    for (; i < n4; i += stride) {
        float4 v = ((const float4*)in)[i];
        u16x4 o;
        o.x = f2bf(v.x); o.y = f2bf(v.y); o.z = f2bf(v.z); o.w = f2bf(v.w);
        ((u16x4*)out)[i] = o;
    }
}

// ---------------- transpose + convert: in [R][C] fp32 -> out [C][R] bf16 ----------------
__global__ void k_transpose_bf(const float* __restrict__ in, u16* __restrict__ out, int R, int C) {
    __shared__ float t[32][33];
    int c0 = blockIdx.x * 32, r0 = blockIdx.y * 32;
    int tx = threadIdx.x, ty = threadIdx.y;
    #pragma unroll
    for (int j = 0; j < 32; j += 8)
        t[ty + j][tx] = in[(size_t)(r0 + ty + j) * C + c0 + tx];
    __syncthreads();
    #pragma unroll
    for (int j = 0; j < 32; j += 8)
        out[(size_t)(c0 + ty + j) * R + r0 + tx] = f2bf(t[tx][ty + j]);
}

// ---------------- GEMM C[M][N] = A[M][K] @ BT[N][K]^T  (m97 structure, unchanged) --------
template<bool OUT_BF16>
__global__ __launch_bounds__(256, 2)
void k_gemm_bt(const u16* __restrict__ A, const u16* __restrict__ BT,
               void* __restrict__ C, int N, int K) {
    __shared__ u16 Asm[128 * 32];
    __shared__ u16 Bsm[128 * 32];
    const int tid  = threadIdx.x;
    const int lane = tid & 63;
    const int wave = tid >> 6;

    const int gx   = gridDim.x;
    const int nwg  = gx * gridDim.y;
    const int orig = blockIdx.y * gx + blockIdx.x;
    const int wg   = (orig & 7) * (nwg >> 3) + (orig >> 3);
    const int bx   = wg % gx;
    const int by   = wg / gx;

    const long row0 = (long)by * 128;
    const long col0 = (long)bx * 128;
    const int  wr = (wave >> 1) * 64;
    const int  wc = (wave & 1) * 64;

    f32x4 acc[4][4] = {};

    const int ar0 = lane >> 2;
    const int ak  = (lane & 3) * 8;

    for (int kb = 0; kb < K; kb += 32) {
        #pragma unroll
        for (int i = 0; i < 2; i++) {
            int ch = wave * 2 + i;
            int r  = ch * 16 + ar0;
            gload_lds16(A  + (row0 + r) * (size_t)K + kb + ak, &Asm[ch * 512]);
            gload_lds16(BT + (col0 + r) * (size_t)K + kb + ak, &Bsm[ch * 512]);
        }
        __syncthreads();
        short8 af[4], bfr[4];
        #pragma unroll
        for (int m = 0; m < 4; m++)
            af[m] = *(const short8*)&Asm[(wr + m * 16 + (lane & 15)) * 32 + (lane >> 4) * 8];
        #pragma unroll
        for (int n = 0; n < 4; n++)
            bfr[n] = *(const short8*)&Bsm[(wc + n * 16 + (lane & 15)) * 32 + (lane >> 4) * 8];
        #pragma unroll
        for (int m = 0; m < 4; m++)
            #pragma unroll
            for (int n = 0; n < 4; n++)
                acc[m][n] = __builtin_amdgcn_mfma_f32_16x16x32_bf16(af[m], bfr[n], acc[m][n], 0, 0, 0);
        __syncthreads();
    }

    const int rl = (lane >> 4) * 4;
    const int cl = lane & 15;
    #pragma unroll
    for (int m = 0; m < 4; m++)
        #pragma unroll
        for (int n = 0; n < 4; n++)
            #pragma unroll
            for (int r = 0; r < 4; r++) {
                long row = row0 + wr + m * 16 + rl + r;
                long col = col0 + wc + n * 16 + cl;
                if constexpr (OUT_BF16)
                    ((u16*)C)[row * (size_t)N + col] = f2bf(acc[m][n][r]);
                else
                    ((float*)C)[row * (size_t)N + col] = acc[m][n][r];
            }
}

// ---------------- Flash attention v3: swapped-operand 32x32, in-register softmax --------
// grid: 1024 blocks (8 qi x 128 bh), longest-first. Block = 4 waves x 32 q-rows = 128 q.
// KVBLK = 64. Swapped QK^T: S^T = K·Q^T (lane owns q = lane&31). Swapped PV: O^T = V^T·P^T.
#define SCALE_L2E 0.18033688011112042f  // (1/sqrt(64)) * log2(e)

__global__ __launch_bounds__(256, 2)
void k_attn(const u16* __restrict__ qkv, u16* __restrict__ y) {
    constexpr int S = 1024, E = 1024, TE = 3072;
    __shared__ u16 Kt[64 * 64];   // [kv][d], swizzled rows (128B)
    __shared__ u16 Vt[64 * 64];   // [d][kv], swizzled rows (128B)

    const int tid  = threadIdx.x;
    const int lane = tid & 63;
    const int l31  = lane & 31;
    const int hA   = lane >> 5;
    const int wave = tid >> 6;

    const int qi = 7 - (int)(blockIdx.x >> 7);   // longest first
    const int bh = blockIdx.x & 127;
    const int b  = bh >> 4;
    const int h  = bh & 15;
    const int q0 = qi * 128;
    const size_t rowbase = (size_t)b * S;
    const int qg = q0 + wave * 32 + l31;         // this lane's q-row

    // Q fragments: lane holds Q[qg][kd*16 + hA*8 + 0..7] for kd=0..3
    short8 qf[4];
    {
        const u16* qp = qkv + (rowbase + qg) * TE + h * 64 + hA * 8;
        #pragma unroll
        for (int kd = 0; kd < 4; kd++) qf[kd] = *(const short8*)(qp + kd * 16);
    }

    f32x16 o0 = {}, o1 = {};          // O^T: lane col q=l31, rows d = (r&3)+8*(r>>2)+4*hA (+32 for o1)
    float ms = -1e30f, lsum = 0.f;    // running max (exp2-scaled) and denom, per q-row

    // staging indices
    const int kr0 = (wave << 3) + (lane >> 3);
    const int kcb = (lane & 7) * 16;
    const int vkv = (tid >> 3) * 2;
    const int vdc = (tid & 7) * 8;

    const int ntiles = 2 * qi + 2;
    for (int t = 0; t < ntiles; ++t) {
        const int kv0 = t * 64;
        __syncthreads();
        // ---- stage K via global_load_lds with pre-swizzled source ----
        #pragma unroll
        for (int it = 0; it < 2; it++) {
            int r = kr0 + it * 32;
            const char* src = (const char*)qkv
                + (((rowbase + kv0 + r) * TE + E + h * 64) << 1) + (kcb ^ swz(r));
            gload_lds16(src, (char*)Kt + wave * 1024 + it * 4096);
        }
        // ---- stage V^T: coalesced row loads, swizzled b32 pair writes ----
        {
            const u16* vsrc = qkv + (rowbase + kv0 + vkv) * TE + 2 * E + h * 64 + vdc;
            short8 v0 = *(const short8*)vsrc;
            short8 v1 = *(const short8*)(vsrc + TE);
            #pragma unroll
            for (int j = 0; j < 8; j++) {
                int d = vdc + j;
                unsigned val = (unsigned)(u16)v0[j] | ((unsigned)(u16)v1[j] << 16);
                *(unsigned*)((char*)Vt + d * 128 + ((vkv * 2) ^ swz(d))) = val;
            }
        }
        __syncthreads();

        const bool active = (kv0 <= q0 + wave * 32 + 31);
        if (!active) continue;   // wave-uniform; all waves still hit next iter's barrier

        // ---- QK^T (swapped): S^T[kv][q], two 32-kv tiles ----
        f32x16 s0 = {}, s1 = {};
        #pragma unroll
        for (int kd = 0; kd < 4; kd++) {
            int r0 = l31, r1 = 32 + l31;
            short8 ka0 = *(const short8*)((const char*)Kt + r0 * 128 + ((kd * 32 + hA * 16) ^ swz(r0)));
            short8 ka1 = *(const short8*)((const char*)Kt + r1 * 128 + ((kd * 32 + hA * 16) ^ swz(r1)));
            s0 = __builtin_amdgcn_mfma_f32_32x32x16_bf16(ka0, qf[kd], s0, 0, 0, 0);
            s1 = __builtin_amdgcn_mfma_f32_32x32x16_bf16(ka1, qf[kd], s1, 0, 0, 0);
        }

        // ---- causal mask: gate vs the wave's MIN q-row (bug fixed from r3) ----
        if (kv0 + 63 > q0 + wave * 32) {
            #pragma unroll
            for (int r = 0; r < 16; r++) {
                int kvr = kv0 + ((r & 3) + 8 * (r >> 2) + 4 * hA);
                if (kvr > qg)      s0[r] = -1e30f;
                if (kvr + 32 > qg) s1[r] = -1e30f;
            }
        }

        // ---- online softmax: per-lane scalar m, defer-rescale (THR=8 in exp2 units) ----
        float pm = s0[0];
        #pragma unroll
        for (int r = 1; r < 16; r++) pm = fmaxf(pm, s0[r]);
        #pragma unroll
        for (int r = 0; r < 16; r++) pm = fmaxf(pm, s1[r]);
        pm = fmaxf(pm, __shfl_xor(pm, 32));
        float pms = pm * SCALE_L2E;
        if (__any(pms - ms > 8.0f)) {
            float msn = fmaxf(ms, pms);
            float alpha = exp2f(ms - msn);
            ms = msn;
            lsum *= alpha;
            #pragma unroll
            for (int r = 0; r < 16; r++) { o0[r] *= alpha; o1[r] *= alpha; }
        }

        // ---- P = exp2(s*scale - ms); row-sum in-register ----
        float part = 0.f;
        #pragma unroll
        for (int r = 0; r < 16; r++) {
            float p0 = exp2f(s0[r] * SCALE_L2E - ms);
            float p1 = exp2f(s1[r] * SCALE_L2E - ms);
            s0[r] = p0; s1[r] = p1;
            part += p0 + p1;
        }
        lsum += part + __shfl_xor(part, 32);

        // ---- P -> bf16 dwords (cvt_pk), 8 per 32-kv tile ----
        unsigned w0[8], w1[8];
        #pragma unroll
        for (int j = 0; j < 8; j++) {
            asm("v_cvt_pk_bf16_f32 %0, %1, %2" : "=v"(w0[j]) : "v"(s0[2 * j]), "v"(s0[2 * j + 1]));
            asm("v_cvt_pk_bf16_f32 %0, %1, %2" : "=v"(w1[j]) : "v"(s1[2 * j]), "v"(s1[2 * j + 1]));
        }

        // ---- PV (swapped): O^T += V^T · P^T; P^T B-frag built via permlane32_swap ----
        #define PV_TILE(W, ST)                                                              \
        {                                                                                   \
            _Pragma("unroll")                                                               \
            for (int kkl = 0; kkl < 2; kkl++) {                                             \
                unsigned a  = W[4 * kkl],     bsw = W[4 * kkl + 2];                         \
                unsigned a2 = W[4 * kkl + 1], b2  = W[4 * kkl + 3];                         \
                swap32(a, bsw); swap32(a2, b2);                                             \
                union { int4 i; short8 s; } u;                                              \
                u.i = make_int4((int)a, (int)a2, (int)bsw, (int)b2);                        \
                {                                                                           \
                    int row = l31;                                                          \
                    short8 va = *(const short8*)((const char*)Vt + row * 128                \
                                  + (((ST) * 64 + kkl * 32 + hA * 16) ^ swz(row)));         \
                    o0 = __builtin_amdgcn_mfma_f32_32x32x16_bf16(va, u.s, o0, 0, 0, 0);     \
                }                                                                           \
                {                                                                           \
                    int row = 32 + l31;                                                     \
                    short8 va = *(const short8*)((const char*)Vt + row * 128                \
                                  + (((ST) * 64 + kkl * 32 + hA * 16) ^ swz(row)));         \
                    o1 = __builtin_amdgcn_mfma_f32_32x32x16_bf16(va, u.s, o1, 0, 0, 0);     \
                }                                                                           \
            }                                                                               \
        }
        PV_TILE(w0, 0)
        PV_TILE(w1, 1)
        #undef PV_TILE
    }

    // ---- epilogue: normalize, transpose O^T -> O via LDS (once per block), store bf16 --
    __syncthreads();   // all tiles done reading Kt/Vt
    float rinv = 1.0f / lsum;
    u16* Ot = (wave < 2 ? Kt : Vt) + (wave & 1) * 2048;   // 32 rows x 64 d per wave (4KB)
    const int X = (l31 & 7) << 4;
    #pragma unroll
    for (int rq = 0; rq < 4; rq++) {
        u16x4 pk0, pk1;
        #pragma unroll
        for (int j = 0; j < 4; j++) {
            pk0[j] = f2bf(o0[4 * rq + j] * rinv);    // d = 8*rq + 4*hA + j
            pk1[j] = f2bf(o1[4 * rq + j] * rinv);    // d = 32 + 8*rq + 4*hA + j
        }
        *(u16x4*)((char*)Ot + l31 * 128 + ((16 * rq + 8 * hA) ^ X))      = pk0;
        *(u16x4*)((char*)Ot + l31 * 128 + ((64 + 16 * rq + 8 * hA) ^ X)) = pk1;
    }
    __syncthreads();
    #pragma unroll
    for (int p = 0; p < 4; p++) {
        int row = p * 8 + (lane >> 3);               // 0..31 within wave's tile
        int cc  = lane & 7;                          // 16B chunk (8 d-elems)
        short8 vv = *(const short8*)((const char*)Ot + row * 128
                      + ((cc * 16) ^ ((row & 7) << 4)));
        *(short8*)(y + (rowbase + q0 + wave * 32 + row) * E + h * 64 + cc * 8) = vv;
    }
}

// ---------------- launch ----------------
extern "C" void kernel_launch(void* const* d_in, const int* in_sizes, int n_in,
                              void* d_out, int out_size, void* d_ws, size_t ws_size,
                              hipStream_t stream) {
    const float* x     = (const float*)d_in[0];   // [8,1024,1024]
    const float* Wattn = (const float*)d_in[1];   // [1024,3072]
    const float* Wproj = (const float*)d_in[2];   // [1024,1024]
    float* out = (float*)d_out;                   // [8,1024,1024] fp32

    char* ws = (char*)d_ws;
    u16* buf0 = (u16*)ws;                                  // x_bf16, later y_bf16 (16.78 MB)
    u16* wT   = (u16*)(ws + 16777216);                     // W^T bf16 (6.29 MB, reused)
    u16* qkv  = (u16*)(ws + 16777216 + 6291456);           // [8192][3072] bf16 (50.3 MB)

    // x -> bf16
    k_conv_x<<<2048, 256, 0, stream>>>(x, buf0, 8388608 / 4);
    // W_attn^T -> bf16 [3072][1024]
    k_transpose_bf<<<dim3(3072 / 32, 1024 / 32), dim3(32, 8), 0, stream>>>(Wattn, wT, 1024, 3072);
    // qkv = x @ W_attn   (bf16 out)
    k_gemm_bt<true><<<dim3(3072 / 128, 8192 / 128), 256, 0, stream>>>(buf0, wT, qkv, 3072, 1024);
    // W_proj^T -> bf16 [1024][1024]
    k_transpose_bf<<<dim3(1024 / 32, 1024 / 32), dim3(32, 8), 0, stream>>>(Wproj, wT, 1024, 1024);
    // flash attention -> y (reuses buf0)
    k_attn<<<dim3(1024), 256, 0, stream>>>(qkv, buf0);
    // out = y @ W_proj  (fp32 out)
    k_gemm_bt<false><<<dim3(1024 / 128, 8192 / 128), 256, 0, stream>>>(buf0, wT, out, 1024, 1024);
}